// Round 32
// baseline (117.193 us; speedup 1.0000x reference)
//
#include <hip/hip_runtime.h>
#include <hip/hip_fp16.h>

typedef _Float16 half8 __attribute__((ext_vector_type(8)));
typedef _Float16 half4 __attribute__((ext_vector_type(4)));
typedef float f32x4 __attribute__((ext_vector_type(4)));
typedef unsigned uint4v __attribute__((ext_vector_type(4)));

// ---------- binned CSR build ----------
#define RANGE    512
#define RSH      9
#define CAP      17408          // mean E/NB=16327 + 8 sigma
#define T_TILE   16384          // edges per binpass block (512 thr x 32)

// ---------- helpers ----------

__device__ __forceinline__ void unp8(uint4v v, float* f) {
#pragma unroll
    for (int k = 0; k < 4; ++k) {
        unsigned w = v[k];
        __half2 h2 = *reinterpret_cast<__half2*>(&w);
        float2 t = __half22float2(h2);
        f[2 * k] = t.x; f[2 * k + 1] = t.y;
    }
}

__device__ __forceinline__ void acc8(float* a, uint4v v) {
#pragma unroll
    for (int k = 0; k < 4; ++k) {
        unsigned w = v[k];
        __half2 h2 = *reinterpret_cast<__half2*>(&w);
        float2 t = __half22float2(h2);
        a[2 * k]     += t.x;
        a[2 * k + 1] += t.y;
    }
}

__device__ __forceinline__ uint4v pk8(const float* o) {
    uint4v r;
#pragma unroll
    for (int k = 0; k < 4; ++k) {
        __half2 h2 = __floats2half2_rn(o[2 * k], o[2 * k + 1]);
        r[k] = *reinterpret_cast<unsigned*>(&h2);
    }
    return r;
}

// wave-inclusive scan via shfl_up (64-lane)
__device__ __forceinline__ int wave_incl_scan(int v, int lane) {
#pragma unroll
    for (int off = 1; off < 64; off <<= 1) {
        int u = __shfl_up(v, off);
        if (lane >= off) v += u;
    }
    return v;
}

// ---------------- fat kernel (512 thr): binpass (blocks < binBlocks) || gemm1 raw ----------------
// gcursor starts at 0 (memset); global positions are b*CAP + cursor.
// Writeout: per-bucket runs (no sdst array) -> LDS ~72 KB -> 2 blocks/CU.

__global__ __launch_bounds__(512) void binpass_gemm1(const int* __restrict__ src,
                                                     const int* __restrict__ dst, int E,
                                                     int* __restrict__ gcursor,
                                                     unsigned* __restrict__ pairbuf,
                                                     int binBlocks,
                                                     const float* __restrict__ x,
                                                     const float* __restrict__ W1,
                                                     __half* __restrict__ g1, int N) {
    if (blockIdx.x >= binBlocks) {
        // ---- gemm1 raw: 8 waves x 16 rows = 128 rows/block ----
        int wave = threadIdx.x >> 6;
        int lane = threadIdx.x & 63;
        int R0 = (blockIdx.x - binBlocks) * 128 + wave * 16;
        if (R0 >= N) return;
        int m = lane & 15;
        int kb = (lane >> 4) * 8;
        int row = R0 + m;
        int rowc = min(row, N - 1);

        half8 bfrag[4];
#pragma unroll
        for (int kk = 0; kk < 4; ++kk) {
#pragma unroll
            for (int j = 0; j < 8; ++j)
                bfrag[kk][j] = (_Float16)W1[(kk * 32 + kb + j) * 16 + m];
        }
        const float* xr = x + (size_t)rowc * 128;
        float4 u[8];
#pragma unroll
        for (int kk = 0; kk < 4; ++kk) {
            u[2 * kk]     = *reinterpret_cast<const float4*>(xr + kk * 32 + kb);
            u[2 * kk + 1] = *reinterpret_cast<const float4*>(xr + kk * 32 + kb + 4);
        }
        f32x4 acc = {0.f, 0.f, 0.f, 0.f};
#pragma unroll
        for (int kk = 0; kk < 4; ++kk) {
            half8 a;
            a[0] = (_Float16)u[2 * kk].x;     a[1] = (_Float16)u[2 * kk].y;
            a[2] = (_Float16)u[2 * kk].z;     a[3] = (_Float16)u[2 * kk].w;
            a[4] = (_Float16)u[2 * kk + 1].x; a[5] = (_Float16)u[2 * kk + 1].y;
            a[6] = (_Float16)u[2 * kk + 1].z; a[7] = (_Float16)u[2 * kk + 1].w;
            acc = __builtin_amdgcn_mfma_f32_16x16x32_f16(a, bfrag[kk], acc, 0, 0, 0);
        }
#pragma unroll
        for (int i = 0; i < 4; ++i) {
            int r = R0 + (lane >> 4) * 4 + i;
            if (r < N) g1[(size_t)r * 16 + m] = __float2half(acc[i]);
        }
        return;
    }
    // ---- binpass (512 thr x 32 edges) ----
    __shared__ unsigned sbuf[T_TILE];
    __shared__ int lcount2[512], lplace2[512];
    __shared__ int gbase[256];
    __shared__ int loff[257];
    __shared__ int wsum4[4];
    int t = threadIdx.x;
    int par = t & 1;
    int lane = t & 63;
    int wid8 = t >> 6;                 // wave id 0..7
    int base = blockIdx.x * T_TILE;
    int ecount = min(T_TILE, E - base);

    lcount2[t] = 0;
    __syncthreads();

    unsigned pk[32];
    int bn[32];
#pragma unroll
    for (int k4 = 0; k4 < 8; ++k4) {
        int i = base + (t + k4 * 512) * 4;
        if (i + 3 < E) {
            int4 sv = *reinterpret_cast<const int4*>(src + i);
            int4 dv = *reinterpret_cast<const int4*>(dst + i);
            int ss[4] = {sv.x, sv.y, sv.z, sv.w};
            int dd[4] = {dv.x, dv.y, dv.z, dv.w};
#pragma unroll
            for (int m = 0; m < 4; ++m) {
                int k = k4 * 4 + m;
                bn[k] = dd[m] >> RSH;
                pk[k] = ((unsigned)ss[m] << RSH) | (unsigned)(dd[m] & (RANGE - 1));
                atomicAdd(&lcount2[2 * bn[k] + par], 1);
            }
        } else {
#pragma unroll
            for (int m = 0; m < 4; ++m) {
                int k = k4 * 4 + m;
                int ii = i + m;
                if (ii < E) {
                    int s = src[ii], d = dst[ii];
                    bn[k] = d >> RSH;
                    pk[k] = ((unsigned)s << RSH) | (unsigned)(d & (RANGE - 1));
                    atomicAdd(&lcount2[2 * bn[k] + par], 1);
                } else bn[k] = -1;
            }
        }
    }
    __syncthreads();
    // scan over 256 buckets by first 4 waves
    if (t < 256) {
        int wid = t >> 6;
        int c0 = lcount2[2 * t], c1 = lcount2[2 * t + 1];
        int c = c0 + c1;
        int v = wave_incl_scan(c, lane);
        if (lane == 63) wsum4[wid] = v;
        __syncthreads();
        int add = 0;
#pragma unroll
        for (int w = 0; w < 4; ++w) add += (w < wid) ? wsum4[w] : 0;
        int ex = v + add - c;
        loff[t] = ex;
        if (t == 255) loff[256] = v + add;   // total = ecount
        lplace2[2 * t] = ex;
        lplace2[2 * t + 1] = ex + c0;
        if (c > 0) gbase[t] = t * CAP + atomicAdd(&gcursor[t], c) - ex;
    } else {
        __syncthreads();
    }
    __syncthreads();
#pragma unroll
    for (int k = 0; k < 32; ++k) {
        if (bn[k] >= 0) {
            int b = bn[k];
            int pos = atomicAdd(&lplace2[2 * b + par], 1);
            sbuf[pos] = pk[k];
        }
    }
    __syncthreads();
    // per-bucket run writeout: wave w handles buckets w, w+8, ...
    for (int b = wid8; b < 256; b += 8) {
        int st = loff[b], en = loff[b + 1];
        if (st >= en) continue;
        int gb0 = gbase[b];
        for (int i = st + lane; i < en; i += 64)
            pairbuf[gb0 + i] = sbuf[i];
    }
}

// ---------------- bucket_build: 1024 thr, wave-scans, LDS-staged, + g1 scaling + zero-rows ----------------

__global__ __launch_bounds__(1024) void bucket_build(const unsigned* __restrict__ pairbuf,
                                                     const int* __restrict__ gcursor,
                                                     int NB, int N, int E,
                                                     int* __restrict__ rowptr,
                                                     float* __restrict__ dinv,
                                                     int* __restrict__ eidx,
                                                     __half* __restrict__ g1,
                                                     __half* __restrict__ g2) {
    __shared__ unsigned spair[CAP];
    __shared__ int lcnt[RANGE];
    __shared__ int lsc[RANGE];
    __shared__ int sscan[256];
    __shared__ int bsum4[4];
    __shared__ int wsum8[8];
    int b = blockIdx.x, t = threadIdx.x;
    int lane = t & 63;

    if (t < 256) sscan[t] = (t < NB) ? gcursor[t] : 0;
    if (t < RANGE) lcnt[t] = 0;
    __syncthreads();
    int sv = 0;
    if (t < 256) {
        sv = wave_incl_scan(sscan[t], lane);
        if (lane == 63) bsum4[t >> 6] = sv;
    }
    __syncthreads();
    if (t < 256) {
        int swid = t >> 6;
        int add = 0;
#pragma unroll
        for (int w = 0; w < 4; ++w) add += (w < swid) ? bsum4[w] : 0;
        sscan[t] = sv + add;
    }
    __syncthreads();
    int gb = (b == 0) ? 0 : sscan[b - 1];
    int cnt = gcursor[b];
    const unsigned* pb = pairbuf + (size_t)b * CAP;

    for (int i = t; i < cnt; i += 1024) {
        unsigned p = pb[i];
        spair[i] = p;
        atomicAdd(&lcnt[p & (RANGE - 1)], 1);
    }
    __syncthreads();
    int myc = 0, incl = 0;
    if (t < RANGE) {
        myc = lcnt[t];
        incl = wave_incl_scan(myc, lane);
        if (lane == 63) wsum8[t >> 6] = incl;
    }
    __syncthreads();
    if (t < RANGE) {
        int lwid = t >> 6;
        int add = 0;
#pragma unroll
        for (int w = 0; w < 8; ++w) add += (w < lwid) ? wsum8[w] : 0;
        incl += add;
        int ex = incl - myc;
        int node = b * RANGE + t;
        if (node < N) {
            rowptr[node] = gb + ex;
            float di = rsqrtf((float)myc + 1.0f);
            dinv[node] = di;
            __half* gr = g1 + (size_t)node * 16;
            uint4v v0 = *reinterpret_cast<const uint4v*>(gr);
            uint4v v1 = *reinterpret_cast<const uint4v*>(gr + 8);
            float f[8];
            unp8(v0, f);
#pragma unroll
            for (int k = 0; k < 8; ++k) f[k] *= di;
            *reinterpret_cast<uint4v*>(gr) = pk8(f);
            unp8(v1, f);
#pragma unroll
            for (int k = 0; k < 8; ++k) f[k] *= di;
            *reinterpret_cast<uint4v*>(gr + 8) = pk8(f);
        } else if (node == N) {
            uint4v z = {0u, 0u, 0u, 0u};
            *reinterpret_cast<uint4v*>(g1 + (size_t)N * 16)     = z;
            *reinterpret_cast<uint4v*>(g1 + (size_t)N * 16 + 8) = z;
            *reinterpret_cast<uint4v*>(g2 + (size_t)N * 16)     = z;
            *reinterpret_cast<uint4v*>(g2 + (size_t)N * 16 + 8) = z;
        }
        if (b == 0 && t == 0) rowptr[N] = E;
        lsc[t] = gb + ex;
    }
    __syncthreads();
    for (int i = t; i < cnt; i += 1024) {
        unsigned p = spair[i];
        int pos = atomicAdd(&lsc[p & (RANGE - 1)], 1);
        eidx[pos] = (int)(p >> RSH);
    }
}

// ---------------- gather1: 16 lanes/node (h x es8); one-iteration masked loop ----------------

__global__ __launch_bounds__(256) void gather1_kernel(const int* __restrict__ rowptr,
                                                      const int* __restrict__ eidx,
                                                      const __half* __restrict__ g1,
                                                      const float* __restrict__ dinv,
                                                      const float* __restrict__ b1,
                                                      __half* __restrict__ g2, int N) {
    int gid = blockIdx.x * blockDim.x + threadIdx.x;
    int d = gid >> 4;
    if (d >= N) return;
    int sub = threadIdx.x & 15;
    int h = sub & 1, es = sub >> 1;      // es in 0..7
    int f0 = h * 8;
    int lo = rowptr[d], hi = rowptr[d + 1];
    float di = dinv[d];
    uint4v svh = *reinterpret_cast<const uint4v*>(g1 + (size_t)d * 16 + f0);

    float a[8] = {0, 0, 0, 0, 0, 0, 0, 0};
    for (int j = lo + es; j < hi; j += 64) {
        int idx[8];
#pragma unroll
        for (int k = 0; k < 8; ++k) {
            int jj = j + 8 * k;
            idx[k] = (jj < hi) ? eidx[jj] : N;
        }
        uint4v v[8];
#pragma unroll
        for (int k = 0; k < 8; ++k)
            v[k] = *reinterpret_cast<const uint4v*>(g1 + (size_t)idx[k] * 16 + f0);
#pragma unroll
        for (int k = 0; k < 8; ++k) acc8(a, v[k]);
    }
#pragma unroll
    for (int k = 0; k < 8; ++k) {
        a[k] += __shfl_xor(a[k], 2);
        a[k] += __shfl_xor(a[k], 4);
        a[k] += __shfl_xor(a[k], 8);
    }
    if (es == 0) {
        float sf[8];
        unp8(svh, sf);
        f32x4 bb0 = *reinterpret_cast<const f32x4*>(b1 + f0);
        f32x4 bb1 = *reinterpret_cast<const f32x4*>(b1 + f0 + 4);
        float o[8];
#pragma unroll
        for (int k = 0; k < 4; ++k) {
            o[k]     = fmaxf(di * (a[k] + sf[k]) + bb0[k], 0.0f) * di;
            o[k + 4] = fmaxf(di * (a[k + 4] + sf[k + 4]) + bb1[k], 0.0f) * di;
        }
        *reinterpret_cast<uint4v*>(g2 + (size_t)d * 16 + f0) = pk8(o);
    }
}

// ---------------- gather2: 16 lanes/node; agg2 -> g3 fp16 (self-loop + dinv) ----------------

__global__ __launch_bounds__(256) void gather2_kernel(const int* __restrict__ rowptr,
                                                      const int* __restrict__ eidx,
                                                      const __half* __restrict__ g2,
                                                      const float* __restrict__ dinv,
                                                      __half* __restrict__ g3, int N) {
    int gid = blockIdx.x * blockDim.x + threadIdx.x;
    int d = gid >> 4;
    if (d >= N) return;
    int sub = threadIdx.x & 15;
    int h = sub & 1, es = sub >> 1;      // es in 0..7
    int f0 = h * 8;
    int lo = rowptr[d], hi = rowptr[d + 1];
    float di = dinv[d];
    uint4v svh = *reinterpret_cast<const uint4v*>(g2 + (size_t)d * 16 + f0);

    float a[8] = {0, 0, 0, 0, 0, 0, 0, 0};
    for (int j = lo + es; j < hi; j += 64) {
        int idx[8];
#pragma unroll
        for (int k = 0; k < 8; ++k) {
            int jj = j + 8 * k;
            idx[k] = (jj < hi) ? eidx[jj] : N;
        }
        uint4v v[8];
#pragma unroll
        for (int k = 0; k < 8; ++k)
            v[k] = *reinterpret_cast<const uint4v*>(g2 + (size_t)idx[k] * 16 + f0);
#pragma unroll
        for (int k = 0; k < 8; ++k) acc8(a, v[k]);
    }
#pragma unroll
    for (int k = 0; k < 8; ++k) {
        a[k] += __shfl_xor(a[k], 2);
        a[k] += __shfl_xor(a[k], 4);
        a[k] += __shfl_xor(a[k], 8);
    }
    if (es == 0) {
        float sf[8];
        unp8(svh, sf);
        float o[8];
#pragma unroll
        for (int k = 0; k < 8; ++k) o[k] = di * (a[k] + sf[k]);
        *reinterpret_cast<uint4v*>(g3 + (size_t)d * 16 + f0) = pk8(o);
    }
}

// ---------------- gemm2 via MFMA: out = g3 @ W2 + b2   [N,16]@[16,128] ----------------

__global__ __launch_bounds__(256) void gemm2_mfma(const __half* __restrict__ g3,
                                                  const float* __restrict__ W2,
                                                  const float* __restrict__ b2,
                                                  float* __restrict__ out, int N) {
    int wave = threadIdx.x >> 6;
    int lane = threadIdx.x & 63;
    int R0 = blockIdx.x * 64 + wave * 16;
    if (R0 >= N) return;
    int nl = lane & 15;
    int q = lane >> 4;
    int row = R0 + nl;
    int rowc = min(row, N - 1);

    half4 afrag = *reinterpret_cast<const half4*>(g3 + (size_t)rowc * 16 + q * 4);

    f32x4 dacc[8];
#pragma unroll
    for (int ct = 0; ct < 8; ++ct) {
        half4 bfrag;
#pragma unroll
        for (int jj = 0; jj < 4; ++jj)
            bfrag[jj] = (_Float16)W2[(q * 4 + jj) * 128 + ct * 16 + nl];
        f32x4 z = {0.f, 0.f, 0.f, 0.f};
        dacc[ct] = __builtin_amdgcn_mfma_f32_16x16x16f16(afrag, bfrag, z, 0, 0, 0);
    }

    float bias[8];
#pragma unroll
    for (int ct = 0; ct < 8; ++ct) bias[ct] = b2[ct * 16 + nl];

    int rbase = R0 + q * 4;
#pragma unroll
    for (int i = 0; i < 4; ++i) {
        int r = rbase + i;
        if (r < N) {
            float* orow = out + (size_t)r * 128 + nl;
#pragma unroll
            for (int ct = 0; ct < 8; ++ct) orow[ct * 16] = dacc[ct][i] + bias[ct];
        }
    }
}

// ---------------- launch ----------------

extern "C" void kernel_launch(void* const* d_in, const int* in_sizes, int n_in,
                              void* d_out, int out_size, void* d_ws, size_t ws_size,
                              hipStream_t stream) {
    const float* x  = (const float*)d_in[0];
    const int*   ei = (const int*)d_in[1];
    const float* W1 = (const float*)d_in[2];
    const float* b1 = (const float*)d_in[3];
    const float* W2 = (const float*)d_in[4];
    const float* b2 = (const float*)d_in[5];
    float* out = (float*)d_out;

    const int N = in_sizes[0] / 128;
    const int E = in_sizes[1] / 2;
    const int* src = ei;
    const int* dst = ei + E;
    const int NB = (N + RANGE - 1) / RANGE;

    // ws (4B units): [pairbuf NB*CAP][gcursor NB][rowptr N+1][eidx E][dinv N][g1 8(N+1)][g2 8(N+1)][g3 8N]
    unsigned* pairbuf = (unsigned*)d_ws;
    int* gcursor = (int*)(pairbuf + (size_t)NB * CAP);
    int* rowptr  = gcursor + NB;
    int* eidx    = rowptr + (N + 1);
    float* dinv  = (float*)(eidx + E);
    __half* g1 = (__half*)(dinv + N);
    __half* g2 = g1 + 16 * (N + 1);
    __half* g3 = g2 + 16 * (N + 1);

    const int B = 256;
    const int binBlocks   = (E + T_TILE - 1) / T_TILE;
    const int gemmBlocks  = (N + 127) / 128;     // 128 rows per 512-thr block
    const int gemm2Blocks = (N + 63) / 64;
    hipMemsetAsync(gcursor, 0, (size_t)NB * sizeof(int), stream);
    binpass_gemm1<<<binBlocks + gemmBlocks, 512, 0, stream>>>(src, dst, E, gcursor, pairbuf,
                                                              binBlocks, x, W1, g1, N);
    bucket_build<<<NB, 1024, 0, stream>>>(pairbuf, gcursor, NB, N, E, rowptr, dinv, eidx, g1, g2);
    gather1_kernel<<<(N * 16 + B - 1) / B, B, 0, stream>>>(rowptr, eidx, g1, dinv, b1, g2, N);
    gather2_kernel<<<(N * 16 + B - 1) / B, B, 0, stream>>>(rowptr, eidx, g2, dinv, g3, N);
    gemm2_mfma<<<gemm2Blocks, B, 0, stream>>>(g3, W2, b2, out, N);
}

// Round 33
// 115.854 us; speedup vs baseline: 1.0116x; 1.0116x over previous
//
#include <hip/hip_runtime.h>
#include <hip/hip_fp16.h>

typedef _Float16 half8 __attribute__((ext_vector_type(8)));
typedef _Float16 half4 __attribute__((ext_vector_type(4)));
typedef float f32x4 __attribute__((ext_vector_type(4)));
typedef unsigned uint4v __attribute__((ext_vector_type(4)));

// ---------- binned CSR build ----------
#define RANGE    512
#define RSH      9
#define CAP      17408          // mean E/NB=16327 + 8 sigma
#define T_TILE   16384          // edges per binpass block (512 thr x 32)

// ---------- helpers ----------

__device__ __forceinline__ void unp8(uint4v v, float* f) {
#pragma unroll
    for (int k = 0; k < 4; ++k) {
        unsigned w = v[k];
        __half2 h2 = *reinterpret_cast<__half2*>(&w);
        float2 t = __half22float2(h2);
        f[2 * k] = t.x; f[2 * k + 1] = t.y;
    }
}

__device__ __forceinline__ void acc8(float* a, uint4v v) {
#pragma unroll
    for (int k = 0; k < 4; ++k) {
        unsigned w = v[k];
        __half2 h2 = *reinterpret_cast<__half2*>(&w);
        float2 t = __half22float2(h2);
        a[2 * k]     += t.x;
        a[2 * k + 1] += t.y;
    }
}

__device__ __forceinline__ uint4v pk8(const float* o) {
    uint4v r;
#pragma unroll
    for (int k = 0; k < 4; ++k) {
        __half2 h2 = __floats2half2_rn(o[2 * k], o[2 * k + 1]);
        r[k] = *reinterpret_cast<unsigned*>(&h2);
    }
    return r;
}

// wave-inclusive scan via shfl_up (64-lane)
__device__ __forceinline__ int wave_incl_scan(int v, int lane) {
#pragma unroll
    for (int off = 1; off < 64; off <<= 1) {
        int u = __shfl_up(v, off);
        if (lane >= off) v += u;
    }
    return v;
}

// ---------------- fat kernel (512 thr): binpass (blocks < binBlocks) || gemm1 raw ----------------
// gcursor starts at 0 (memset); global positions are b*CAP + cursor.

__global__ __launch_bounds__(512) void binpass_gemm1(const int* __restrict__ src,
                                                     const int* __restrict__ dst, int E,
                                                     int* __restrict__ gcursor,
                                                     unsigned* __restrict__ pairbuf,
                                                     int binBlocks,
                                                     const float* __restrict__ x,
                                                     const float* __restrict__ W1,
                                                     __half* __restrict__ g1, int N) {
    if (blockIdx.x >= binBlocks) {
        // ---- gemm1 raw: 8 waves x 16 rows = 128 rows/block ----
        int wave = threadIdx.x >> 6;
        int lane = threadIdx.x & 63;
        int R0 = (blockIdx.x - binBlocks) * 128 + wave * 16;
        if (R0 >= N) return;
        int m = lane & 15;
        int kb = (lane >> 4) * 8;
        int row = R0 + m;
        int rowc = min(row, N - 1);

        half8 bfrag[4];
#pragma unroll
        for (int kk = 0; kk < 4; ++kk) {
#pragma unroll
            for (int j = 0; j < 8; ++j)
                bfrag[kk][j] = (_Float16)W1[(kk * 32 + kb + j) * 16 + m];
        }
        const float* xr = x + (size_t)rowc * 128;
        float4 u[8];
#pragma unroll
        for (int kk = 0; kk < 4; ++kk) {
            u[2 * kk]     = *reinterpret_cast<const float4*>(xr + kk * 32 + kb);
            u[2 * kk + 1] = *reinterpret_cast<const float4*>(xr + kk * 32 + kb + 4);
        }
        f32x4 acc = {0.f, 0.f, 0.f, 0.f};
#pragma unroll
        for (int kk = 0; kk < 4; ++kk) {
            half8 a;
            a[0] = (_Float16)u[2 * kk].x;     a[1] = (_Float16)u[2 * kk].y;
            a[2] = (_Float16)u[2 * kk].z;     a[3] = (_Float16)u[2 * kk].w;
            a[4] = (_Float16)u[2 * kk + 1].x; a[5] = (_Float16)u[2 * kk + 1].y;
            a[6] = (_Float16)u[2 * kk + 1].z; a[7] = (_Float16)u[2 * kk + 1].w;
            acc = __builtin_amdgcn_mfma_f32_16x16x32_f16(a, bfrag[kk], acc, 0, 0, 0);
        }
#pragma unroll
        for (int i = 0; i < 4; ++i) {
            int r = R0 + (lane >> 4) * 4 + i;
            if (r < N) g1[(size_t)r * 16 + m] = __float2half(acc[i]);
        }
        return;
    }
    // ---- binpass (512 thr x 32 edges) ----
    __shared__ unsigned sbuf[T_TILE];
    __shared__ int sdst[T_TILE];
    __shared__ int lcount2[512], lplace2[512];
    __shared__ int gbase[256];
    __shared__ int wsum4[4];
    int t = threadIdx.x;
    int par = t & 1;
    int lane = t & 63;
    int base = blockIdx.x * T_TILE;
    int ecount = min(T_TILE, E - base);

    lcount2[t] = 0;
    __syncthreads();

    unsigned pk[32];
    int bn[32];
#pragma unroll
    for (int k4 = 0; k4 < 8; ++k4) {
        int i = base + (t + k4 * 512) * 4;
        if (i + 3 < E) {
            int4 sv = *reinterpret_cast<const int4*>(src + i);
            int4 dv = *reinterpret_cast<const int4*>(dst + i);
            int ss[4] = {sv.x, sv.y, sv.z, sv.w};
            int dd[4] = {dv.x, dv.y, dv.z, dv.w};
#pragma unroll
            for (int m = 0; m < 4; ++m) {
                int k = k4 * 4 + m;
                bn[k] = dd[m] >> RSH;
                pk[k] = ((unsigned)ss[m] << RSH) | (unsigned)(dd[m] & (RANGE - 1));
                atomicAdd(&lcount2[2 * bn[k] + par], 1);
            }
        } else {
#pragma unroll
            for (int m = 0; m < 4; ++m) {
                int k = k4 * 4 + m;
                int ii = i + m;
                if (ii < E) {
                    int s = src[ii], d = dst[ii];
                    bn[k] = d >> RSH;
                    pk[k] = ((unsigned)s << RSH) | (unsigned)(d & (RANGE - 1));
                    atomicAdd(&lcount2[2 * bn[k] + par], 1);
                } else bn[k] = -1;
            }
        }
    }
    __syncthreads();
    // scan over 256 buckets by first 4 waves
    if (t < 256) {
        int wid = t >> 6;
        int c0 = lcount2[2 * t], c1 = lcount2[2 * t + 1];
        int c = c0 + c1;
        int v = wave_incl_scan(c, lane);
        if (lane == 63) wsum4[wid] = v;
        __syncthreads();
        int add = 0;
#pragma unroll
        for (int w = 0; w < 4; ++w) add += (w < wid) ? wsum4[w] : 0;
        int ex = v + add - c;
        lplace2[2 * t] = ex;
        lplace2[2 * t + 1] = ex + c0;
        if (c > 0) gbase[t] = t * CAP + atomicAdd(&gcursor[t], c) - ex;
    } else {
        __syncthreads();
    }
    __syncthreads();
#pragma unroll
    for (int k = 0; k < 32; ++k) {
        if (bn[k] >= 0) {
            int b = bn[k];
            int pos = atomicAdd(&lplace2[2 * b + par], 1);
            sbuf[pos] = pk[k];
            sdst[pos] = gbase[b] + pos;
        }
    }
    __syncthreads();
    for (int i = t; i < ecount; i += 512) {
        pairbuf[sdst[i]] = sbuf[i];
    }
}

// ---------------- bucket_build: 1024 thr, wave-scans, LDS-staged, + g1 scaling + zero-rows ----------------

__global__ __launch_bounds__(1024) void bucket_build(const unsigned* __restrict__ pairbuf,
                                                     const int* __restrict__ gcursor,
                                                     int NB, int N, int E,
                                                     int* __restrict__ rowptr,
                                                     float* __restrict__ dinv,
                                                     int* __restrict__ eidx,
                                                     __half* __restrict__ g1,
                                                     __half* __restrict__ g2) {
    __shared__ unsigned spair[CAP];
    __shared__ int lcnt[RANGE];
    __shared__ int lsc[RANGE];
    __shared__ int sscan[256];
    __shared__ int bsum4[4];
    __shared__ int wsum8[8];
    int b = blockIdx.x, t = threadIdx.x;
    int lane = t & 63;

    if (t < 256) sscan[t] = (t < NB) ? gcursor[t] : 0;
    if (t < RANGE) lcnt[t] = 0;
    __syncthreads();
    int sv = 0;
    if (t < 256) {
        sv = wave_incl_scan(sscan[t], lane);
        if (lane == 63) bsum4[t >> 6] = sv;
    }
    __syncthreads();
    if (t < 256) {
        int swid = t >> 6;
        int add = 0;
#pragma unroll
        for (int w = 0; w < 4; ++w) add += (w < swid) ? bsum4[w] : 0;
        sscan[t] = sv + add;
    }
    __syncthreads();
    int gb = (b == 0) ? 0 : sscan[b - 1];
    int cnt = gcursor[b];
    const unsigned* pb = pairbuf + (size_t)b * CAP;

    for (int i = t; i < cnt; i += 1024) {
        unsigned p = pb[i];
        spair[i] = p;
        atomicAdd(&lcnt[p & (RANGE - 1)], 1);
    }
    __syncthreads();
    int myc = 0, incl = 0;
    if (t < RANGE) {
        myc = lcnt[t];
        incl = wave_incl_scan(myc, lane);
        if (lane == 63) wsum8[t >> 6] = incl;
    }
    __syncthreads();
    if (t < RANGE) {
        int lwid = t >> 6;
        int add = 0;
#pragma unroll
        for (int w = 0; w < 8; ++w) add += (w < lwid) ? wsum8[w] : 0;
        incl += add;
        int ex = incl - myc;
        int node = b * RANGE + t;
        if (node < N) {
            rowptr[node] = gb + ex;
            float di = rsqrtf((float)myc + 1.0f);
            dinv[node] = di;
            __half* gr = g1 + (size_t)node * 16;
            uint4v v0 = *reinterpret_cast<const uint4v*>(gr);
            uint4v v1 = *reinterpret_cast<const uint4v*>(gr + 8);
            float f[8];
            unp8(v0, f);
#pragma unroll
            for (int k = 0; k < 8; ++k) f[k] *= di;
            *reinterpret_cast<uint4v*>(gr) = pk8(f);
            unp8(v1, f);
#pragma unroll
            for (int k = 0; k < 8; ++k) f[k] *= di;
            *reinterpret_cast<uint4v*>(gr + 8) = pk8(f);
        } else if (node == N) {
            uint4v z = {0u, 0u, 0u, 0u};
            *reinterpret_cast<uint4v*>(g1 + (size_t)N * 16)     = z;
            *reinterpret_cast<uint4v*>(g1 + (size_t)N * 16 + 8) = z;
            *reinterpret_cast<uint4v*>(g2 + (size_t)N * 16)     = z;
            *reinterpret_cast<uint4v*>(g2 + (size_t)N * 16 + 8) = z;
        }
        if (b == 0 && t == 0) rowptr[N] = E;
        lsc[t] = gb + ex;
    }
    __syncthreads();
    for (int i = t; i < cnt; i += 1024) {
        unsigned p = spair[i];
        int pos = atomicAdd(&lsc[p & (RANGE - 1)], 1);
        eidx[pos] = (int)(p >> RSH);
    }
}

// ---------------- gather1: 16 lanes/node (h x es8); one-iteration masked loop ----------------

__global__ __launch_bounds__(256) void gather1_kernel(const int* __restrict__ rowptr,
                                                      const int* __restrict__ eidx,
                                                      const __half* __restrict__ g1,
                                                      const float* __restrict__ dinv,
                                                      const float* __restrict__ b1,
                                                      __half* __restrict__ g2, int N) {
    int gid = blockIdx.x * blockDim.x + threadIdx.x;
    int d = gid >> 4;
    if (d >= N) return;
    int sub = threadIdx.x & 15;
    int h = sub & 1, es = sub >> 1;      // es in 0..7
    int f0 = h * 8;
    int lo = rowptr[d], hi = rowptr[d + 1];
    float di = dinv[d];
    uint4v svh = *reinterpret_cast<const uint4v*>(g1 + (size_t)d * 16 + f0);

    float a[8] = {0, 0, 0, 0, 0, 0, 0, 0};
    for (int j = lo + es; j < hi; j += 64) {
        int idx[8];
#pragma unroll
        for (int k = 0; k < 8; ++k) {
            int jj = j + 8 * k;
            idx[k] = (jj < hi) ? eidx[jj] : N;
        }
        uint4v v[8];
#pragma unroll
        for (int k = 0; k < 8; ++k)
            v[k] = *reinterpret_cast<const uint4v*>(g1 + (size_t)idx[k] * 16 + f0);
#pragma unroll
        for (int k = 0; k < 8; ++k) acc8(a, v[k]);
    }
#pragma unroll
    for (int k = 0; k < 8; ++k) {
        a[k] += __shfl_xor(a[k], 2);
        a[k] += __shfl_xor(a[k], 4);
        a[k] += __shfl_xor(a[k], 8);
    }
    if (es == 0) {
        float sf[8];
        unp8(svh, sf);
        f32x4 bb0 = *reinterpret_cast<const f32x4*>(b1 + f0);
        f32x4 bb1 = *reinterpret_cast<const f32x4*>(b1 + f0 + 4);
        float o[8];
#pragma unroll
        for (int k = 0; k < 4; ++k) {
            o[k]     = fmaxf(di * (a[k] + sf[k]) + bb0[k], 0.0f) * di;
            o[k + 4] = fmaxf(di * (a[k + 4] + sf[k + 4]) + bb1[k], 0.0f) * di;
        }
        *reinterpret_cast<uint4v*>(g2 + (size_t)d * 16 + f0) = pk8(o);
    }
}

// ---------------- gather2: 16 lanes/node; agg2 -> g3 fp16 (self-loop + dinv) ----------------

__global__ __launch_bounds__(256) void gather2_kernel(const int* __restrict__ rowptr,
                                                      const int* __restrict__ eidx,
                                                      const __half* __restrict__ g2,
                                                      const float* __restrict__ dinv,
                                                      __half* __restrict__ g3, int N) {
    int gid = blockIdx.x * blockDim.x + threadIdx.x;
    int d = gid >> 4;
    if (d >= N) return;
    int sub = threadIdx.x & 15;
    int h = sub & 1, es = sub >> 1;      // es in 0..7
    int f0 = h * 8;
    int lo = rowptr[d], hi = rowptr[d + 1];
    float di = dinv[d];
    uint4v svh = *reinterpret_cast<const uint4v*>(g2 + (size_t)d * 16 + f0);

    float a[8] = {0, 0, 0, 0, 0, 0, 0, 0};
    for (int j = lo + es; j < hi; j += 64) {
        int idx[8];
#pragma unroll
        for (int k = 0; k < 8; ++k) {
            int jj = j + 8 * k;
            idx[k] = (jj < hi) ? eidx[jj] : N;
        }
        uint4v v[8];
#pragma unroll
        for (int k = 0; k < 8; ++k)
            v[k] = *reinterpret_cast<const uint4v*>(g2 + (size_t)idx[k] * 16 + f0);
#pragma unroll
        for (int k = 0; k < 8; ++k) acc8(a, v[k]);
    }
#pragma unroll
    for (int k = 0; k < 8; ++k) {
        a[k] += __shfl_xor(a[k], 2);
        a[k] += __shfl_xor(a[k], 4);
        a[k] += __shfl_xor(a[k], 8);
    }
    if (es == 0) {
        float sf[8];
        unp8(svh, sf);
        float o[8];
#pragma unroll
        for (int k = 0; k < 8; ++k) o[k] = di * (a[k] + sf[k]);
        *reinterpret_cast<uint4v*>(g3 + (size_t)d * 16 + f0) = pk8(o);
    }
}

// ---------------- gemm2 via MFMA: out = g3 @ W2 + b2   [N,16]@[16,128] ----------------

__global__ __launch_bounds__(256) void gemm2_mfma(const __half* __restrict__ g3,
                                                  const float* __restrict__ W2,
                                                  const float* __restrict__ b2,
                                                  float* __restrict__ out, int N) {
    int wave = threadIdx.x >> 6;
    int lane = threadIdx.x & 63;
    int R0 = blockIdx.x * 64 + wave * 16;
    if (R0 >= N) return;
    int nl = lane & 15;
    int q = lane >> 4;
    int row = R0 + nl;
    int rowc = min(row, N - 1);

    half4 afrag = *reinterpret_cast<const half4*>(g3 + (size_t)rowc * 16 + q * 4);

    f32x4 dacc[8];
#pragma unroll
    for (int ct = 0; ct < 8; ++ct) {
        half4 bfrag;
#pragma unroll
        for (int jj = 0; jj < 4; ++jj)
            bfrag[jj] = (_Float16)W2[(q * 4 + jj) * 128 + ct * 16 + nl];
        f32x4 z = {0.f, 0.f, 0.f, 0.f};
        dacc[ct] = __builtin_amdgcn_mfma_f32_16x16x16f16(afrag, bfrag, z, 0, 0, 0);
    }

    float bias[8];
#pragma unroll
    for (int ct = 0; ct < 8; ++ct) bias[ct] = b2[ct * 16 + nl];

    int rbase = R0 + q * 4;
#pragma unroll
    for (int i = 0; i < 4; ++i) {
        int r = rbase + i;
        if (r < N) {
            float* orow = out + (size_t)r * 128 + nl;
#pragma unroll
            for (int ct = 0; ct < 8; ++ct) orow[ct * 16] = dacc[ct][i] + bias[ct];
        }
    }
}

// ---------------- launch ----------------

extern "C" void kernel_launch(void* const* d_in, const int* in_sizes, int n_in,
                              void* d_out, int out_size, void* d_ws, size_t ws_size,
                              hipStream_t stream) {
    const float* x  = (const float*)d_in[0];
    const int*   ei = (const int*)d_in[1];
    const float* W1 = (const float*)d_in[2];
    const float* b1 = (const float*)d_in[3];
    const float* W2 = (const float*)d_in[4];
    const float* b2 = (const float*)d_in[5];
    float* out = (float*)d_out;

    const int N = in_sizes[0] / 128;
    const int E = in_sizes[1] / 2;
    const int* src = ei;
    const int* dst = ei + E;
    const int NB = (N + RANGE - 1) / RANGE;

    // ws (4B units): [pairbuf NB*CAP][gcursor NB][rowptr N+1][eidx E][dinv N][g1 8(N+1)][g2 8(N+1)][g3 8N]
    unsigned* pairbuf = (unsigned*)d_ws;
    int* gcursor = (int*)(pairbuf + (size_t)NB * CAP);
    int* rowptr  = gcursor + NB;
    int* eidx    = rowptr + (N + 1);
    float* dinv  = (float*)(eidx + E);
    __half* g1 = (__half*)(dinv + N);
    __half* g2 = g1 + 16 * (N + 1);
    __half* g3 = g2 + 16 * (N + 1);

    const int B = 256;
    const int binBlocks   = (E + T_TILE - 1) / T_TILE;
    const int gemmBlocks  = (N + 127) / 128;     // 128 rows per 512-thr block
    const int gemm2Blocks = (N + 63) / 64;
    hipMemsetAsync(gcursor, 0, (size_t)NB * sizeof(int), stream);
    binpass_gemm1<<<binBlocks + gemmBlocks, 512, 0, stream>>>(src, dst, E, gcursor, pairbuf,
                                                              binBlocks, x, W1, g1, N);
    bucket_build<<<NB, 1024, 0, stream>>>(pairbuf, gcursor, NB, N, E, rowptr, dinv, eidx, g1, g2);
    gather1_kernel<<<(N * 16 + B - 1) / B, B, 0, stream>>>(rowptr, eidx, g1, dinv, b1, g2, N);
    gather2_kernel<<<(N * 16 + B - 1) / B, B, 0, stream>>>(rowptr, eidx, g2, dinv, g3, N);
    gemm2_mfma<<<gemm2Blocks, B, 0, stream>>>(g3, W2, b2, out, N);
}